// Round 6
// baseline (421.340 us; speedup 1.0000x reference)
//
#include <hip/hip_runtime.h>
#include <math.h>

// Problem constants
#define B_  8
#define D_  1024
#define T_  2048
#define CD_ 256
#define CS_ 8192
#define N_  (B_*T_)

#define NSPLIT 8
#define CODES_PER_SPLIT (CS_/NSPLIT)   // 1024
#define DELTA 1.5f                     // score-units; >> 2*bf16 dot error

// scan geometry: 4 waves * 64 rows = 256 rows/block; 64-code LDS tiles
#define SCAN_WAVES 4
#define ROWS_PER_WAVE 64
#define SCAN_ROWS 256
#define TILE_CODES 64

// ws layout (float offsets). Total ~16 MB.
#define WS_ZEN   0                        // bf16 [N][256]   (2,097,152 float slots)
#define WS_CBB   2097152                  // bf16 [CS][256]  (1,048,576)
#define WS_WINT  (WS_CBB + 1048576)       // f32 [D][CD]
#define WS_WOB   (WS_WINT + D_*CD_)       // bf16 [D][CD] (131072 float slots)
#define WS_C2    (WS_WOB + D_*CD_/2)      // f32 [CS]
#define WS_BESTQ (WS_C2 + CS_)            // f32 [NSPLIT][N]; row 0 becomes thr
#define WS_CNT   (WS_BESTQ + NSPLIT*N_)   // int [N]
#define WS_CAND  (WS_CNT + N_)            // int [N][16]
#define WS_IDX   (WS_CAND + N_*16)        // int [N]

// d_out layout (floats): z_q, indices(as float), z_e
#define OUT_ZQ  0
#define OUT_IDX (B_*D_*T_)
#define OUT_ZE  (OUT_IDX + B_*T_)

using short8v = __attribute__((ext_vector_type(8))) short;
using float4v = __attribute__((ext_vector_type(4))) float;

__device__ __forceinline__ float wave_sum64(float v) {
#pragma unroll
  for (int off = 32; off >= 1; off >>= 1) v += __shfl_xor(v, off);
  return v;
}

__device__ __forceinline__ unsigned short f2bf_rne(float f) {
  unsigned int u = __float_as_uint(f);
  u += 0x7fffu + ((u >> 16) & 1u);
  return (unsigned short)(u >> 16);
}

__device__ __forceinline__ void gload_lds16(const void* g, void* l) {
  __builtin_amdgcn_global_load_lds(
      (const __attribute__((address_space(1))) void*)g,
      (__attribute__((address_space(3))) void*)l, 16, 0, 0);
}

// ---- fused prep: one kernel, block-range dispatch ----
// [0,256): w_inT   [256,1280): wob   [1280,3328): c2   [3328,4352): cbb
__global__ __launch_bounds__(256) void prep_all(
    const float* __restrict__ in_v, const float* __restrict__ in_g,
    const float* __restrict__ out_v, const float* __restrict__ out_g,
    const float* __restrict__ cb,
    float* __restrict__ w_inT, unsigned short* __restrict__ wob,
    float* __restrict__ c2, unsigned short* __restrict__ cbb) {
  __shared__ float sh[4];
  int blk = blockIdx.x, tid = threadIdx.x;
  if (blk < CD_) {
    // w_inT[d][c] = in_g[c] * in_v[c][d] / ||in_v[c,:]||
    int c = blk;
    float v[4]; float s = 0.f;
#pragma unroll
    for (int i = 0; i < 4; ++i) {
      v[i] = in_v[c * D_ + tid + 256 * i];
      s = fmaf(v[i], v[i], s);
    }
    s = wave_sum64(s);
    if ((tid & 63) == 0) sh[tid >> 6] = s;
    __syncthreads();
    float tot = sh[0] + sh[1] + sh[2] + sh[3];
    float scale = in_g[c] / sqrtf(tot);
#pragma unroll
    for (int i = 0; i < 4; ++i)
      w_inT[(tid + 256 * i) * CD_ + c] = v[i] * scale;
  } else if (blk < CD_ + D_) {
    // wob[d][c] = bf16( out_g[d] * out_v[d][c] / ||out_v[d,:]|| )
    int d = blk - CD_;
    float v = out_v[d * CD_ + tid];
    float s = wave_sum64(v * v);
    if ((tid & 63) == 0) sh[tid >> 6] = s;
    __syncthreads();
    float tot = sh[0] + sh[1] + sh[2] + sh[3];
    float scale = out_g[d] / sqrtf(tot);
    wob[d * CD_ + tid] = f2bf_rne(v * scale);
  } else if (blk < CD_ + D_ + CS_ / 4) {
    // c2[s] = sum_c codebook[s][c]^2   (4 waves, one row each)
    int w = tid >> 6, lane = tid & 63;
    int s = (blk - CD_ - D_) * 4 + w;
    float acc = 0.f;
#pragma unroll
    for (int i = 0; i < 4; ++i) {
      float v = cb[(size_t)s * CD_ + lane + 64 * i];
      acc = fmaf(v, v, acc);
    }
    acc = wave_sum64(acc);
    if (lane == 0) c2[s] = acc;
  } else {
    // cbb = bf16(codebook), row-major
    size_t i = (size_t)(blk - CD_ - D_ - CS_ / 4) * 256 + tid;  // octet index
    float4 v0 = *(const float4*)&cb[i * 8];
    float4 v1 = *(const float4*)&cb[i * 8 + 4];
    float f[8] = {v0.x, v0.y, v0.z, v0.w, v1.x, v1.y, v1.z, v1.w};
    unsigned short us[8];
#pragma unroll
    for (int m = 0; m < 8; ++m) us[m] = f2bf_rne(f[m]);
    *(uint4*)&cbb[i * 8] = *(uint4*)&us[0];
  }
}

// ---- K1: z_e = w_in @ z + b, fused transpose+bf16 (zeN) epilogue ----
// tile 128c x 128t, 256 threads, microtile 8x8 (two 4-blocks per dim at
// 16B lane stride -> conflict-free b128). LDS roofline: 64B/thread/kk per
// 128 FLOP. Double-buffered global_load_lds staging, one barrier per K-tile.
// Per-output K-order = sequential kk (bit-identical to prior rounds).
__global__ __launch_bounds__(256) void ze_gemm(
    const float* __restrict__ z, const float* __restrict__ w_inT,
    const float* __restrict__ in_b, float* __restrict__ out,
    unsigned short* __restrict__ zeN) {
  __shared__ __align__(16) float At[2][32 * 128];   // 16 KB each
  __shared__ __align__(16) float Bt[2][32 * 128];   // 16 KB each
  int tid = threadIdx.x, tx = tid & 15, ty = tid >> 4;
  int w = tid >> 6, l = tid & 63;
  int t0 = blockIdx.x * 128, c0 = blockIdx.y * 128, b = blockIdx.z;
  const float* zb = z + (size_t)b * D_ * T_;

  int kk2 = l >> 5;           // 0/1: which kk-row within a 1KB segment
  int seg = (l & 31) * 16;    // byte offset within 512B row

  auto stage = [&](int buf, int kc) {
#pragma unroll
    for (int i = 0; i < 4; ++i) {
      int g = w * 4 + i;
      int kk = g * 2 + kk2;
      gload_lds16((const char*)&w_inT[(size_t)(kc + kk) * CD_ + c0] + seg,
                  (char*)&At[buf][0] + g * 1024);
      gload_lds16((const char*)&zb[(size_t)(kc + kk) * T_ + t0] + seg,
                  (char*)&Bt[buf][0] + g * 1024);
    }
  };

  float acc[8][8] = {};
  stage(0, 0);
  __syncthreads();
  int cur = 0;
  for (int kt = 0; kt < D_ / 32; ++kt) {
    if (kt + 1 < D_ / 32) stage(cur ^ 1, (kt + 1) * 32);
#pragma unroll 8
    for (int kk = 0; kk < 32; ++kk) {
      float a[8], bv[8];
      *(float4*)&a[0] = *(const float4*)&At[cur][kk * 128 + ty * 4];
      *(float4*)&a[4] = *(const float4*)&At[cur][kk * 128 + 64 + ty * 4];
      *(float4*)&bv[0] = *(const float4*)&Bt[cur][kk * 128 + tx * 4];
      *(float4*)&bv[4] = *(const float4*)&Bt[cur][kk * 128 + 64 + tx * 4];
#pragma unroll
      for (int j = 0; j < 8; ++j)
#pragma unroll
        for (int m = 0; m < 8; ++m)
          acc[j][m] = fmaf(a[j], bv[m], acc[j][m]);
    }
    __syncthreads();
    cur ^= 1;
  }

  // bias
  float bias[8];
#pragma unroll
  for (int jg = 0; jg < 2; ++jg)
#pragma unroll
    for (int j = 0; j < 4; ++j)
      bias[jg * 4 + j] = in_b[c0 + jg * 64 + ty * 4 + j];

  // z_e fp32 out: per c, two float4 stores (t-groups at +0 / +64)
#pragma unroll
  for (int jg = 0; jg < 2; ++jg)
#pragma unroll
    for (int j = 0; j < 4; ++j) {
      int jj = jg * 4 + j;
      int c = c0 + jg * 64 + ty * 4 + j;
      float4 o0, o1;
      o0.x = acc[jj][0] + bias[jj]; o0.y = acc[jj][1] + bias[jj];
      o0.z = acc[jj][2] + bias[jj]; o0.w = acc[jj][3] + bias[jj];
      o1.x = acc[jj][4] + bias[jj]; o1.y = acc[jj][5] + bias[jj];
      o1.z = acc[jj][6] + bias[jj]; o1.w = acc[jj][7] + bias[jj];
      size_t rb = OUT_ZE + (size_t)(b * CD_ + c) * T_ + t0;
      *(float4*)&out[rb + tx * 4] = o0;
      *(float4*)&out[rb + 64 + tx * 4] = o1;
    }

  // zeN bf16 transposed: per t, two 8B stores (c-groups at +0 / +64)
#pragma unroll
  for (int mg = 0; mg < 2; ++mg)
#pragma unroll
    for (int m = 0; m < 4; ++m) {
      int mm = mg * 4 + m;
      int t = t0 + mg * 64 + tx * 4 + m;
      size_t rowb = (size_t)(b * T_ + t) * CD_;
      unsigned short usA[4], usB[4];
#pragma unroll
      for (int j = 0; j < 4; ++j) {
        usA[j] = f2bf_rne(acc[j][mm] + bias[j]);
        usB[j] = f2bf_rne(acc[4 + j][mm] + bias[4 + j]);
      }
      *(uint2*)&zeN[rowb + c0 + ty * 4] = *(uint2*)&usA[0];
      *(uint2*)&zeN[rowb + c0 + 64 + ty * 4] = *(uint2*)&usB[0];
    }
}

// ---- K2: MFMA coarse scan, LDS-staged double-buffered ----
template <int COLLECT>
__global__ __launch_bounds__(256, 2) void vq_scan(
    const unsigned short* __restrict__ zeN, const unsigned short* __restrict__ cbb,
    const float* __restrict__ c2, float* __restrict__ bestq,
    int* __restrict__ cnt, int* __restrict__ cand) {
  __shared__ __align__(16) unsigned short smem[2][TILE_CODES * CD_];  // 2 x 32 KB
  int tid = threadIdx.x;
  int w = tid >> 6, l = tid & 63;
  int lrow = l & 15, lg = l >> 4;
  int rowbase = blockIdx.x * SCAN_ROWS + w * ROWS_PER_WAVE;
  int cq = blockIdx.y;
  int cbase0 = cq * CODES_PER_SPLIT;

  if (COLLECT == 0 && cq == 0)
    cnt[blockIdx.x * SCAN_ROWS + tid] = 0;

  short8v a[4][8];
#pragma unroll
  for (int rf = 0; rf < 4; ++rf)
#pragma unroll
    for (int ks = 0; ks < 8; ++ks)
      a[rf][ks] = *(const short8v*)&zeN[((size_t)(rowbase + rf * 16 + lrow)) * CD_ + ks * 32 + lg * 8];

  float best[16];
  float thr[16];
#pragma unroll
  for (int s = 0; s < 16; ++s) best[s] = -3.4e38f;
  if (COLLECT) {
#pragma unroll
    for (int s = 0; s < 16; ++s) {
      int rf = s >> 2, rg = s & 3;
      thr[s] = bestq[rowbase + rf * 16 + lg * 4 + rg];  // rowmax - DELTA
    }
  }

  int lhalf = l >> 5;
  int lcol = (l & 31) * 16;
  char* smem_b = (char*)&smem[0][0];
  const char* cbb_b = (const char*)cbb;
  int xsw = (lrow & 7) << 4;

  auto stage = [&](int buf, int cbase) {
#pragma unroll
    for (int r = 0; r < 8; ++r) {
      int code = w * 16 + r * 2 + lhalf;
      size_t goff = (size_t)(cbase + code) * 512 + (size_t)(lcol ^ ((code & 7) << 4));
      gload_lds16(cbb_b + goff, smem_b + buf * 32768 + (w * 8 + r) * 1024);
    }
  };

  stage(0, cbase0);
  __syncthreads();

  for (int t = 0; t < CODES_PER_SPLIT / TILE_CODES; ++t) {
    int buf = t & 1;
    int cbase = cbase0 + t * TILE_CODES;
    if (t + 1 < CODES_PER_SPLIT / TILE_CODES)
      stage(buf ^ 1, cbase + TILE_CODES);

    const char* bufb = smem_b + buf * 32768;
#pragma unroll
    for (int cf = 0; cf < 4; ++cf) {
      const char* bbase = bufb + (cf * 16 + lrow) * 512;
      float c2v = c2[cbase + cf * 16 + lrow];
      float4v acc[4];
#pragma unroll
      for (int rf = 0; rf < 4; ++rf) acc[rf] = (float4v){0.f, 0.f, 0.f, 0.f};
#pragma unroll
      for (int ks = 0; ks < 8; ++ks) {
        short8v bfrag = *(const short8v*)(bbase + ((ks * 64 + lg * 16) ^ xsw));
        acc[0] = __builtin_amdgcn_mfma_f32_16x16x32_bf16(a[0][ks], bfrag, acc[0], 0, 0, 0);
        acc[1] = __builtin_amdgcn_mfma_f32_16x16x32_bf16(a[1][ks], bfrag, acc[1], 0, 0, 0);
        acc[2] = __builtin_amdgcn_mfma_f32_16x16x32_bf16(a[2][ks], bfrag, acc[2], 0, 0, 0);
        acc[3] = __builtin_amdgcn_mfma_f32_16x16x32_bf16(a[3][ks], bfrag, acc[3], 0, 0, 0);
      }
      int ci = cbase + cf * 16 + lrow;
      float half_c2 = 0.5f * c2v;
#pragma unroll
      for (int rf = 0; rf < 4; ++rf)
#pragma unroll
        for (int rg = 0; rg < 4; ++rg) {
          float sc = acc[rf][rg] - half_c2;
          int slot = rf * 4 + rg;
          if (COLLECT) {
            if (sc >= thr[slot]) {
              int row = rowbase + rf * 16 + lg * 4 + rg;
              int pos = atomicAdd(&cnt[row], 1);
              if (pos < 16) cand[row * 16 + pos] = ci;
            }
          } else {
            best[slot] = fmaxf(best[slot], sc);
          }
        }
    }
    __syncthreads();
  }

  if (!COLLECT) {
#pragma unroll
    for (int s = 0; s < 16; ++s) {
      float v = best[s];
#pragma unroll
      for (int off = 1; off < 16; off <<= 1) v = fmaxf(v, __shfl_xor(v, off));
      best[s] = v;
    }
    if (lrow == 0) {
#pragma unroll
      for (int s = 0; s < 16; ++s) {
        int rf = s >> 2, rg = s & 3;
        bestq[cq * N_ + rowbase + rf * 16 + lg * 4 + rg] = best[s];
      }
    }
  }
}

// ---- fold split maxima into per-row threshold, in place (row 0 of bestq) ----
__global__ __launch_bounds__(256) void vq_rowthr(float* __restrict__ bestq) {
  int n = blockIdx.x * 256 + threadIdx.x;
  float m = bestq[n];
#pragma unroll
  for (int q = 1; q < NSPLIT; ++q) m = fmaxf(m, bestq[q * N_ + n]);
  bestq[n] = m - DELTA;
}

// ---- exact fp32 rescore of candidates; lexicographic (dist, idx) min ----
__global__ __launch_bounds__(256) void vq_rescore(
    const float* __restrict__ ze, const float* __restrict__ cb,
    const int* __restrict__ cnt, const int* __restrict__ cand,
    float* __restrict__ out, int* __restrict__ idx_ws) {
  int tid = threadIdx.x;
  int n = blockIdx.x * 64 + (tid >> 2);
  int j = tid & 3;
  int b = n >> 11, t = n & (T_ - 1);
  const float* zr = ze + ((size_t)b * CD_) * T_ + t;  // element k at zr[k*T_]
  int m = cnt[n]; if (m > 16) m = 16;
  float bd = 3.4e38f; int bi = 0x7fffffff;
  for (int i = 0; i < m; ++i) {
    int c = cand[n * 16 + i];
    const float* cr = cb + (size_t)c * CD_;
    float d = 0.f;
    for (int k = j; k < CD_; k += 4) {
      float diff = zr[(size_t)k * T_] - cr[k];
      d = fmaf(diff, diff, d);
    }
    d += __shfl_xor(d, 1);
    d += __shfl_xor(d, 2);
    if (d < bd || (d == bd && c < bi)) { bd = d; bi = c; }
  }
  if (j == 0) {
    idx_ws[n] = bi;
    out[OUT_IDX + n] = (float)bi;
  }
}

// ---- K3 (MFMA): z_q = w_out @ codebook[idx] + out_b ----
__global__ __launch_bounds__(256, 2) void zq_mfma(
    const unsigned short* __restrict__ wob, const unsigned short* __restrict__ cbb,
    const float* __restrict__ out_bias, const int* __restrict__ idx,
    float* __restrict__ out) {
  __shared__ __align__(16) unsigned short Bs[64 * CD_];  // 32 KB
  __shared__ int idxs[64];
  int tid = threadIdx.x;
  int w = tid >> 6, l = tid & 63;
  int lrow = l & 15, lg = l >> 4;
  int t0 = blockIdx.x * 64, d0 = blockIdx.y * 256, b = blockIdx.z;
  int rowbase = d0 + w * 64;

  if (tid < 64) idxs[tid] = idx[b * T_ + t0 + tid];

  short8v a[4][8];
#pragma unroll
  for (int rf = 0; rf < 4; ++rf)
#pragma unroll
    for (int ks = 0; ks < 8; ++ks)
      a[rf][ks] = *(const short8v*)&wob[((size_t)(rowbase + rf * 16 + lrow)) * CD_ + ks * 32 + lg * 8];

  __syncthreads();  // idxs ready

  int lhalf = l >> 5;
  int lcol = (l & 31) * 16;
  char* Bs_b = (char*)&Bs[0];
  const char* cbb_b = (const char*)cbb;
#pragma unroll
  for (int r = 0; r < 8; ++r) {
    int t = w * 16 + r * 2 + lhalf;
    int row = idxs[t];
    size_t goff = (size_t)row * 512 + (size_t)(lcol ^ ((t & 7) << 4));
    gload_lds16(cbb_b + goff, Bs_b + (w * 8 + r) * 1024);
  }
  __syncthreads();  // drains vmcnt

  int xsw = (lrow & 7) << 4;
  float4v acc[4][4];
#pragma unroll
  for (int rf = 0; rf < 4; ++rf)
#pragma unroll
    for (int cf = 0; cf < 4; ++cf) acc[rf][cf] = (float4v){0.f, 0.f, 0.f, 0.f};
#pragma unroll
  for (int cf = 0; cf < 4; ++cf) {
    const char* bbase = Bs_b + (cf * 16 + lrow) * 512;
#pragma unroll
    for (int ks = 0; ks < 8; ++ks) {
      short8v bfrag = *(const short8v*)(bbase + ((ks * 64 + lg * 16) ^ xsw));
      acc[0][cf] = __builtin_amdgcn_mfma_f32_16x16x32_bf16(a[0][ks], bfrag, acc[0][cf], 0, 0, 0);
      acc[1][cf] = __builtin_amdgcn_mfma_f32_16x16x32_bf16(a[1][ks], bfrag, acc[1][cf], 0, 0, 0);
      acc[2][cf] = __builtin_amdgcn_mfma_f32_16x16x32_bf16(a[2][ks], bfrag, acc[2][cf], 0, 0, 0);
      acc[3][cf] = __builtin_amdgcn_mfma_f32_16x16x32_bf16(a[3][ks], bfrag, acc[3][cf], 0, 0, 0);
    }
  }
#pragma unroll
  for (int rf = 0; rf < 4; ++rf) {
    float bias[4];
#pragma unroll
    for (int rg = 0; rg < 4; ++rg) bias[rg] = out_bias[rowbase + rf * 16 + lg * 4 + rg];
#pragma unroll
    for (int cf = 0; cf < 4; ++cf) {
      int t = t0 + cf * 16 + lrow;
#pragma unroll
      for (int rg = 0; rg < 4; ++rg) {
        int d = rowbase + rf * 16 + lg * 4 + rg;
        out[OUT_ZQ + (size_t)(b * D_ + d) * T_ + t] = acc[rf][cf][rg] + bias[rg];
      }
    }
  }
}

extern "C" void kernel_launch(void* const* d_in, const int* in_sizes, int n_in,
                              void* d_out, int out_size, void* d_ws,
                              size_t ws_size, hipStream_t stream) {
  const float* z     = (const float*)d_in[0];
  const float* in_v  = (const float*)d_in[1];
  const float* in_g  = (const float*)d_in[2];
  const float* in_b  = (const float*)d_in[3];
  const float* out_v = (const float*)d_in[4];
  const float* out_g = (const float*)d_in[5];
  const float* out_b = (const float*)d_in[6];
  const float* cb    = (const float*)d_in[7];
  float* out = (float*)d_out;
  float* ws  = (float*)d_ws;

  unsigned short* zeN = (unsigned short*)(ws + WS_ZEN);
  unsigned short* cbb = (unsigned short*)(ws + WS_CBB);
  float* w_inT  = ws + WS_WINT;
  unsigned short* wob = (unsigned short*)(ws + WS_WOB);
  float* c2     = ws + WS_C2;
  float* bestq  = ws + WS_BESTQ;
  int*   cnt    = (int*)(ws + WS_CNT);
  int*   cand   = (int*)(ws + WS_CAND);
  int*   idxw   = (int*)(ws + WS_IDX);

  prep_all<<<CD_ + D_ + CS_ / 4 + CS_ * CD_ / 8 / 256, 256, 0, stream>>>(
      in_v, in_g, out_v, out_g, cb, w_inT, wob, c2, cbb);

  ze_gemm<<<dim3(T_ / 128, CD_ / 128, B_), 256, 0, stream>>>(
      z, w_inT, in_b, out, zeN);

  vq_scan<0><<<dim3(N_ / SCAN_ROWS, NSPLIT), 256, 0, stream>>>(
      zeN, cbb, c2, bestq, cnt, cand);
  vq_rowthr<<<N_ / 256, 256, 0, stream>>>(bestq);
  vq_scan<1><<<dim3(N_ / SCAN_ROWS, NSPLIT), 256, 0, stream>>>(
      zeN, cbb, c2, bestq, cnt, cand);
  vq_rescore<<<N_ / 64, 256, 0, stream>>>(out + OUT_ZE, cb, cnt, cand, out, idxw);

  zq_mfma<<<dim3(T_ / 64, D_ / 256, B_), 256, 0, stream>>>(wob, cbb, out_b, idxw, out);
}

// Round 8
// 405.305 us; speedup vs baseline: 1.0396x; 1.0396x over previous
//
#include <hip/hip_runtime.h>
#include <math.h>

// Problem constants
#define B_  8
#define D_  1024
#define T_  2048
#define CD_ 256
#define CS_ 8192
#define N_  (B_*T_)

#define NSPLIT 8
#define CODES_PER_SPLIT (CS_/NSPLIT)   // 1024
#define DELTA 1.5f                     // score-units; >> 2*bf16 dot error

// scan geometry: 4 waves * 64 rows = 256 rows/block; 64-code LDS tiles
#define SCAN_WAVES 4
#define ROWS_PER_WAVE 64
#define SCAN_ROWS 256
#define TILE_CODES 64

// ws layout (float offsets). Total ~15.9 MB (proven size range).
#define WS_ZEN   0                        // bf16 [N][256]   (2,097,152 float slots)
#define WS_CBB   2097152                  // bf16 [CS][256]  (1,048,576)
#define WS_WINT  (WS_CBB + 1048576)       // f32 [D][CD]
#define WS_WOB   (WS_WINT + D_*CD_)       // bf16 [D][CD] (131072 float slots)
#define WS_C2    (WS_WOB + D_*CD_/2)      // f32 [CS]
#define WS_BESTQ (WS_C2 + CS_)            // f32 [NSPLIT][N]; becomes thr
#define WS_CNT   (WS_BESTQ + NSPLIT*N_)   // int [N]
#define WS_CAND  (WS_CNT + N_)            // int [N][16]
#define WS_IDX   (WS_CAND + N_*16)        // int [N]

// d_out layout (floats): z_q, indices(as float), z_e
#define OUT_ZQ  0
#define OUT_IDX (B_*D_*T_)
#define OUT_ZE  (OUT_IDX + B_*T_)

using short8v = __attribute__((ext_vector_type(8))) short;
using float4v = __attribute__((ext_vector_type(4))) float;

__device__ __forceinline__ float wave_sum64(float v) {
#pragma unroll
  for (int off = 32; off >= 1; off >>= 1) v += __shfl_xor(v, off);
  return v;
}

__device__ __forceinline__ unsigned short f2bf_rne(float f) {
  unsigned int u = __float_as_uint(f);
  u += 0x7fffu + ((u >> 16) & 1u);
  return (unsigned short)(u >> 16);
}

__device__ __forceinline__ void gload_lds16(const void* g, void* l) {
  __builtin_amdgcn_global_load_lds(
      (const __attribute__((address_space(1))) void*)g,
      (__attribute__((address_space(3))) void*)l, 16, 0, 0);
}

// ---- fused prep: one kernel, block-range dispatch ----
// [0,256): w_inT  [256,1280): wob  [1280,3328): c2  [3328,4352): cbb
__global__ __launch_bounds__(256) void prep_all(
    const float* __restrict__ in_v, const float* __restrict__ in_g,
    const float* __restrict__ out_v, const float* __restrict__ out_g,
    const float* __restrict__ cb,
    float* __restrict__ w_inT, unsigned short* __restrict__ wob,
    float* __restrict__ c2, unsigned short* __restrict__ cbb) {
  __shared__ float sh[4];
  int blk = blockIdx.x, tid = threadIdx.x;
  if (blk < CD_) {
    int c = blk;
    float v[4]; float s = 0.f;
#pragma unroll
    for (int i = 0; i < 4; ++i) {
      v[i] = in_v[c * D_ + tid + 256 * i];
      s = fmaf(v[i], v[i], s);
    }
    s = wave_sum64(s);
    if ((tid & 63) == 0) sh[tid >> 6] = s;
    __syncthreads();
    float tot = sh[0] + sh[1] + sh[2] + sh[3];
    float scale = in_g[c] / sqrtf(tot);
#pragma unroll
    for (int i = 0; i < 4; ++i)
      w_inT[(tid + 256 * i) * CD_ + c] = v[i] * scale;
  } else if (blk < CD_ + D_) {
    int d = blk - CD_;
    float v = out_v[d * CD_ + tid];
    float s = wave_sum64(v * v);
    if ((tid & 63) == 0) sh[tid >> 6] = s;
    __syncthreads();
    float tot = sh[0] + sh[1] + sh[2] + sh[3];
    float scale = out_g[d] / sqrtf(tot);
    wob[d * CD_ + tid] = f2bf_rne(v * scale);
  } else if (blk < CD_ + D_ + CS_ / 4) {
    int w = tid >> 6, lane = tid & 63;
    int s = (blk - CD_ - D_) * 4 + w;
    float acc = 0.f;
#pragma unroll
    for (int i = 0; i < 4; ++i) {
      float v = cb[(size_t)s * CD_ + lane + 64 * i];
      acc = fmaf(v, v, acc);
    }
    acc = wave_sum64(acc);
    if (lane == 0) c2[s] = acc;
  } else {
    size_t i = (size_t)(blk - CD_ - D_ - CS_ / 4) * 256 + tid;  // octet index
    float4 v0 = *(const float4*)&cb[i * 8];
    float4 v1 = *(const float4*)&cb[i * 8 + 4];
    float f[8] = {v0.x, v0.y, v0.z, v0.w, v1.x, v1.y, v1.z, v1.w};
    unsigned short us[8];
#pragma unroll
    for (int m = 0; m < 8; ++m) us[m] = f2bf_rne(f[m]);
    *(uint4*)&cbb[i * 8] = *(uint4*)&us[0];
  }
}

// ---- K1: z_e = w_in @ z + b, fused transpose+bf16 (zeN) epilogue ----
// R5 geometry: tile 64c x 128t, TK=32, 256 thr, microtile 8c x 4t (2 blk/CU).
// Double-buffered global_load_lds staging; one barrier per K-tile.
// Per-output K-order = sequential kk (bit-identical z_e to R5).
__global__ __launch_bounds__(256) void ze_gemm(
    const float* __restrict__ z, const float* __restrict__ w_inT,
    const float* __restrict__ in_b, float* __restrict__ out,
    unsigned short* __restrict__ zeN) {
  __shared__ __align__(16) float At[2][32 * 64];    // 8 KB each
  __shared__ __align__(16) float Bt[2][32 * 128];   // 16 KB each
  int tid = threadIdx.x, tx = tid & 31, ty = tid >> 5;
  int w = tid >> 6, l = tid & 63;
  int t0 = blockIdx.x * 128, c0 = blockIdx.y * 64, b = blockIdx.z;
  const float* zb = z + (size_t)b * D_ * T_;

  auto stage = [&](int buf, int kc) {
#pragma unroll
    for (int i = 0; i < 2; ++i) {
      int g = w * 2 + i;
      int kk = g * 4 + (l >> 4);
      int c = (l & 15) * 4;
      gload_lds16(&w_inT[(size_t)(kc + kk) * CD_ + c0 + c], &At[buf][g * 256]);
    }
#pragma unroll
    for (int i = 0; i < 4; ++i) {
      int g = w * 4 + i;
      int kk = g * 2 + (l >> 5);
      int t = (l & 31) * 4;
      gload_lds16(&zb[(size_t)(kc + kk) * T_ + t0 + t], &Bt[buf][g * 256]);
    }
  };

  float acc[8][4] = {};
  stage(0, 0);
  __syncthreads();
  int cur = 0;
  for (int kt = 0; kt < D_ / 32; ++kt) {
    if (kt + 1 < D_ / 32) stage(cur ^ 1, (kt + 1) * 32);
#pragma unroll 8
    for (int kk = 0; kk < 32; ++kk) {
      float a[8], bv[4];
      *(float4*)&a[0] = *(const float4*)&At[cur][kk * 64 + ty * 8];
      *(float4*)&a[4] = *(const float4*)&At[cur][kk * 64 + ty * 8 + 4];
      *(float4*)&bv[0] = *(const float4*)&Bt[cur][kk * 128 + tx * 4];
#pragma unroll
      for (int j = 0; j < 8; ++j)
#pragma unroll
        for (int m = 0; m < 4; ++m)
          acc[j][m] = fmaf(a[j], bv[m], acc[j][m]);
    }
    __syncthreads();
    cur ^= 1;
  }

  float bias[8];
#pragma unroll
  for (int j = 0; j < 8; ++j) bias[j] = in_b[c0 + ty * 8 + j];

  // z_e fp32: [b][c][t]
#pragma unroll
  for (int j = 0; j < 8; ++j) {
    int c = c0 + ty * 8 + j;
    float4 o;
    o.x = acc[j][0] + bias[j]; o.y = acc[j][1] + bias[j];
    o.z = acc[j][2] + bias[j]; o.w = acc[j][3] + bias[j];
    *(float4*)&out[OUT_ZE + (size_t)(b * CD_ + c) * T_ + t0 + tx * 4] = o;
  }
  // zeN bf16 transposed: [b*T+t][c], 16B per t-row (8 c's)
#pragma unroll
  for (int m = 0; m < 4; ++m) {
    int t = t0 + tx * 4 + m;
    unsigned short us[8];
#pragma unroll
    for (int j = 0; j < 8; ++j) us[j] = f2bf_rne(acc[j][m] + bias[j]);
    *(uint4*)&zeN[(size_t)(b * T_ + t) * CD_ + c0 + ty * 8] = *(uint4*)&us[0];
  }
}

// ---- K2: MFMA coarse scan, two-pass (proven structure).
// COLLECT=0: per-row best bf16 score per split -> bestq[cq][row].
// COLLECT=1: append codes with score >= thr[row] (thr = rowmax - DELTA).
template <int COLLECT>
__global__ __launch_bounds__(256, 2) void vq_scan(
    const unsigned short* __restrict__ zeN, const unsigned short* __restrict__ cbb,
    const float* __restrict__ c2, float* __restrict__ bestq,
    int* __restrict__ cnt, int* __restrict__ cand) {
  __shared__ __align__(16) unsigned short smem[2][TILE_CODES * CD_];  // 2 x 32 KB
  int tid = threadIdx.x;
  int w = tid >> 6, l = tid & 63;
  int lrow = l & 15, lg = l >> 4;
  int rowbase = blockIdx.x * SCAN_ROWS + w * ROWS_PER_WAVE;
  int cq = blockIdx.y;
  int cbase0 = cq * CODES_PER_SPLIT;

  if (COLLECT == 0 && cq == 0)
    cnt[blockIdx.x * SCAN_ROWS + tid] = 0;

  short8v a[4][8];
#pragma unroll
  for (int rf = 0; rf < 4; ++rf)
#pragma unroll
    for (int ks = 0; ks < 8; ++ks)
      a[rf][ks] = *(const short8v*)&zeN[((size_t)(rowbase + rf * 16 + lrow)) * CD_ + ks * 32 + lg * 8];

  float best[16];
  float thr[16];
#pragma unroll
  for (int s = 0; s < 16; ++s) best[s] = -3.4e38f;
  if (COLLECT) {
#pragma unroll
    for (int s = 0; s < 16; ++s) {
      int rf = s >> 2, rg = s & 3;
      thr[s] = bestq[rowbase + rf * 16 + lg * 4 + rg];  // rowmax - DELTA
    }
  }

  int lhalf = l >> 5;
  int lcol = (l & 31) * 16;
  char* smem_b = (char*)&smem[0][0];
  const char* cbb_b = (const char*)cbb;
  int xsw = (lrow & 7) << 4;

  auto stage = [&](int buf, int cbase) {
#pragma unroll
    for (int r = 0; r < 8; ++r) {
      int code = w * 16 + r * 2 + lhalf;
      size_t goff = (size_t)(cbase + code) * 512 + (size_t)(lcol ^ ((code & 7) << 4));
      gload_lds16(cbb_b + goff, smem_b + buf * 32768 + (w * 8 + r) * 1024);
    }
  };

  stage(0, cbase0);
  __syncthreads();

  for (int t = 0; t < CODES_PER_SPLIT / TILE_CODES; ++t) {
    int buf = t & 1;
    int cbase = cbase0 + t * TILE_CODES;
    if (t + 1 < CODES_PER_SPLIT / TILE_CODES)
      stage(buf ^ 1, cbase + TILE_CODES);

    const char* bufb = smem_b + buf * 32768;
#pragma unroll
    for (int cf = 0; cf < 4; ++cf) {
      const char* bbase = bufb + (cf * 16 + lrow) * 512;
      float c2v = c2[cbase + cf * 16 + lrow];
      float4v acc[4];
#pragma unroll
      for (int rf = 0; rf < 4; ++rf) acc[rf] = (float4v){0.f, 0.f, 0.f, 0.f};
#pragma unroll
      for (int ks = 0; ks < 8; ++ks) {
        short8v bfrag = *(const short8v*)(bbase + ((ks * 64 + lg * 16) ^ xsw));
        acc[0] = __builtin_amdgcn_mfma_f32_16x16x32_bf16(a[0][ks], bfrag, acc[0], 0, 0, 0);
        acc[1] = __builtin_amdgcn_mfma_f32_16x16x32_bf16(a[1][ks], bfrag, acc[1], 0, 0, 0);
        acc[2] = __builtin_amdgcn_mfma_f32_16x16x32_bf16(a[2][ks], bfrag, acc[2], 0, 0, 0);
        acc[3] = __builtin_amdgcn_mfma_f32_16x16x32_bf16(a[3][ks], bfrag, acc[3], 0, 0, 0);
      }
      int ci = cbase + cf * 16 + lrow;
      float half_c2 = 0.5f * c2v;
#pragma unroll
      for (int rf = 0; rf < 4; ++rf)
#pragma unroll
        for (int rg = 0; rg < 4; ++rg) {
          float sc = acc[rf][rg] - half_c2;
          int slot = rf * 4 + rg;
          if (COLLECT) {
            if (sc >= thr[slot]) {
              int row = rowbase + rf * 16 + lg * 4 + rg;
              int pos = atomicAdd(&cnt[row], 1);
              if (pos < 16) cand[row * 16 + pos] = ci;
            }
          } else {
            best[slot] = fmaxf(best[slot], sc);
          }
        }
    }
    __syncthreads();
  }

  if (!COLLECT) {
#pragma unroll
    for (int s = 0; s < 16; ++s) {
      float v = best[s];
#pragma unroll
      for (int off = 1; off < 16; off <<= 1) v = fmaxf(v, __shfl_xor(v, off));
      best[s] = v;
    }
    if (lrow == 0) {
#pragma unroll
      for (int s = 0; s < 16; ++s) {
        int rf = s >> 2, rg = s & 3;
        bestq[cq * N_ + rowbase + rf * 16 + lg * 4 + rg] = best[s];
      }
    }
  }
}

// ---- fold split maxima into per-row threshold, in place (row 0 of bestq) ----
__global__ __launch_bounds__(256) void vq_rowthr(float* __restrict__ bestq) {
  int n = blockIdx.x * 256 + threadIdx.x;
  float m = bestq[n];
#pragma unroll
  for (int q = 1; q < NSPLIT; ++q) m = fmaxf(m, bestq[q * N_ + n]);
  bestq[n] = m - DELTA;
}

// ---- exact fp32 rescore of candidates; lexicographic (dist, idx) min ----
__global__ __launch_bounds__(256) void vq_rescore(
    const float* __restrict__ ze, const float* __restrict__ cb,
    const int* __restrict__ cnt, const int* __restrict__ cand,
    float* __restrict__ out, int* __restrict__ idx_ws) {
  int tid = threadIdx.x;
  int n = blockIdx.x * 64 + (tid >> 2);
  int j = tid & 3;
  int b = n >> 11, t = n & (T_ - 1);
  const float* zr = ze + ((size_t)b * CD_) * T_ + t;  // element k at zr[k*T_]
  int m = cnt[n]; if (m > 16) m = 16;
  float bd = 3.4e38f; int bi = 0x7fffffff;
  for (int i = 0; i < m; ++i) {
    int c = cand[n * 16 + i];
    const float* cr = cb + (size_t)c * CD_;
    float d = 0.f;
    for (int k = j; k < CD_; k += 4) {
      float diff = zr[(size_t)k * T_] - cr[k];
      d = fmaf(diff, diff, d);
    }
    d += __shfl_xor(d, 1);
    d += __shfl_xor(d, 2);
    if (d < bd || (d == bd && c < bi)) { bd = d; bi = c; }
  }
  if (j == 0) {
    idx_ws[n] = bi;
    out[OUT_IDX + n] = (float)bi;
  }
}

// ---- K3 (MFMA): z_q = w_out @ codebook[idx] + out_b ----
__global__ __launch_bounds__(256, 2) void zq_mfma(
    const unsigned short* __restrict__ wob, const unsigned short* __restrict__ cbb,
    const float* __restrict__ out_bias, const int* __restrict__ idx,
    float* __restrict__ out) {
  __shared__ __align__(16) unsigned short Bs[64 * CD_];  // 32 KB
  __shared__ int idxs[64];
  int tid = threadIdx.x;
  int w = tid >> 6, l = tid & 63;
  int lrow = l & 15, lg = l >> 4;
  int t0 = blockIdx.x * 64, d0 = blockIdx.y * 256, b = blockIdx.z;
  int rowbase = d0 + w * 64;

  if (tid < 64) idxs[tid] = idx[b * T_ + t0 + tid];

  short8v a[4][8];
#pragma unroll
  for (int rf = 0; rf < 4; ++rf)
#pragma unroll
    for (int ks = 0; ks < 8; ++ks)
      a[rf][ks] = *(const short8v*)&wob[((size_t)(rowbase + rf * 16 + lrow)) * CD_ + ks * 32 + lg * 8];

  __syncthreads();  // idxs ready

  int lhalf = l >> 5;
  int lcol = (l & 31) * 16;
  char* Bs_b = (char*)&Bs[0];
  const char* cbb_b = (const char*)cbb;
#pragma unroll
  for (int r = 0; r < 8; ++r) {
    int t = w * 16 + r * 2 + lhalf;
    int row = idxs[t];
    size_t goff = (size_t)row * 512 + (size_t)(lcol ^ ((t & 7) << 4));
    gload_lds16(cbb_b + goff, Bs_b + (w * 8 + r) * 1024);
  }
  __syncthreads();  // drains vmcnt

  int xsw = (lrow & 7) << 4;
  float4v acc[4][4];
#pragma unroll
  for (int rf = 0; rf < 4; ++rf)
#pragma unroll
    for (int cf = 0; cf < 4; ++cf) acc[rf][cf] = (float4v){0.f, 0.f, 0.f, 0.f};
#pragma unroll
  for (int cf = 0; cf < 4; ++cf) {
    const char* bbase = Bs_b + (cf * 16 + lrow) * 512;
#pragma unroll
    for (int ks = 0; ks < 8; ++ks) {
      short8v bfrag = *(const short8v*)(bbase + ((ks * 64 + lg * 16) ^ xsw));
      acc[0][cf] = __builtin_amdgcn_mfma_f32_16x16x32_bf16(a[0][ks], bfrag, acc[0][cf], 0, 0, 0);
      acc[1][cf] = __builtin_amdgcn_mfma_f32_16x16x32_bf16(a[1][ks], bfrag, acc[1][cf], 0, 0, 0);
      acc[2][cf] = __builtin_amdgcn_mfma_f32_16x16x32_bf16(a[2][ks], bfrag, acc[2][cf], 0, 0, 0);
      acc[3][cf] = __builtin_amdgcn_mfma_f32_16x16x32_bf16(a[3][ks], bfrag, acc[3][cf], 0, 0, 0);
    }
  }
#pragma unroll
  for (int rf = 0; rf < 4; ++rf) {
    float bias[4];
#pragma unroll
    for (int rg = 0; rg < 4; ++rg) bias[rg] = out_bias[rowbase + rf * 16 + lg * 4 + rg];
#pragma unroll
    for (int cf = 0; cf < 4; ++cf) {
      int t = t0 + cf * 16 + lrow;
#pragma unroll
      for (int rg = 0; rg < 4; ++rg) {
        int d = rowbase + rf * 16 + lg * 4 + rg;
        out[OUT_ZQ + (size_t)(b * D_ + d) * T_ + t] = acc[rf][cf][rg] + bias[rg];
      }
    }
  }
}

extern "C" void kernel_launch(void* const* d_in, const int* in_sizes, int n_in,
                              void* d_out, int out_size, void* d_ws,
                              size_t ws_size, hipStream_t stream) {
  const float* z     = (const float*)d_in[0];
  const float* in_v  = (const float*)d_in[1];
  const float* in_g  = (const float*)d_in[2];
  const float* in_b  = (const float*)d_in[3];
  const float* out_v = (const float*)d_in[4];
  const float* out_g = (const float*)d_in[5];
  const float* out_b = (const float*)d_in[6];
  const float* cb    = (const float*)d_in[7];
  float* out = (float*)d_out;
  float* ws  = (float*)d_ws;

  unsigned short* zeN = (unsigned short*)(ws + WS_ZEN);
  unsigned short* cbb = (unsigned short*)(ws + WS_CBB);
  float* w_inT  = ws + WS_WINT;
  unsigned short* wob = (unsigned short*)(ws + WS_WOB);
  float* c2     = ws + WS_C2;
  float* bestq  = ws + WS_BESTQ;
  int*   cnt    = (int*)(ws + WS_CNT);
  int*   cand   = (int*)(ws + WS_CAND);
  int*   idxw   = (int*)(ws + WS_IDX);

  prep_all<<<CD_ + D_ + CS_ / 4 + CS_ * CD_ / 8 / 256, 256, 0, stream>>>(
      in_v, in_g, out_v, out_g, cb, w_inT, wob, c2, cbb);

  ze_gemm<<<dim3(T_ / 128, CD_ / 64, B_), 256, 0, stream>>>(
      z, w_inT, in_b, out, zeN);

  vq_scan<0><<<dim3(N_ / SCAN_ROWS, NSPLIT), 256, 0, stream>>>(
      zeN, cbb, c2, bestq, cnt, cand);
  vq_rowthr<<<N_ / 256, 256, 0, stream>>>(bestq);
  vq_scan<1><<<dim3(N_ / SCAN_ROWS, NSPLIT), 256, 0, stream>>>(
      zeN, cbb, c2, bestq, cnt, cand);
  vq_rescore<<<N_ / 64, 256, 0, stream>>>(out + OUT_ZE, cb, cnt, cand, out, idxw);

  zq_mfma<<<dim3(T_ / 64, D_ / 256, B_), 256, 0, stream>>>(wob, cbb, out_b, idxw, out);
}